// Round 5
// baseline (170.999 us; speedup 1.0000x reference)
//
#include <hip/hip_runtime.h>
#include <stdint.h>

#define OUT_F   4096
#define IN_F    11008
#define BATCH   64
#define NSUP    43                  // super-blocks per row
#define SB_ROW  344                 // sub-blocks per row
#define IPR     5504                // int32 elements per weight row
#define NKS     8                   // K-splits -> 64 x 8 = 512 blocks = 2/CU exactly
#define XP_BYTES   (4 * 344 * 64 * 16)              // 1,409,024 B
#define PART_ELEMS ((size_t)NKS * BATCH * OUT_F)
#define WS_FULL    (XP_BYTES + PART_ELEMS * 4)

typedef __attribute__((ext_vector_type(8))) short  short8;
typedef __attribute__((ext_vector_type(4))) float  floatx4;
typedef __attribute__((ext_vector_type(4))) int    intx4;

template<int N> struct IC { static constexpr int value = N; };

__device__ __forceinline__ unsigned pack_bf16(float f0, float f1) {
    return __builtin_amdgcn_perm(__float_as_uint(f1), __float_as_uint(f0), 0x07060302u);
}

// global -> LDS direct copy, 16B/lane; dest = wave-uniform base, HW adds lane*16
__device__ __forceinline__ void glds16(const void* g, void* s) {
    __builtin_amdgcn_global_load_lds(
        (const __attribute__((address_space(1))) uint32_t*)g,
        (__attribute__((address_space(3))) uint32_t*)s,
        16, 0, 0);
}

__device__ __forceinline__ void group_fence(void) {
    asm volatile("" ::: "memory");
    __builtin_amdgcn_sched_barrier(0);
}

// ---- pre-pack x into MFMA A-fragment order: xp[(mt*344 + ksb)*64 + l] ----
__global__ __launch_bounds__(256) void xprep_kernel(const float* __restrict__ x,
                                                    intx4* __restrict__ xp) {
    const int ksb = blockIdx.x;            // 0..343
    const int mt  = threadIdx.x >> 6;
    const int l   = threadIdx.x & 63;
    const int lo  = l & 15, hi = l >> 4;
    const float* src = x + (mt * 16 + lo) * IN_F + ksb * 32 + hi * 8;
    floatx4 a0 = *(const floatx4*)src;
    floatx4 a1 = *(const floatx4*)(src + 4);
    intx4 r;
    r.x = pack_bf16(a0.x, a0.y);
    r.y = pack_bf16(a0.z, a0.w);
    r.z = pack_bf16(a1.x, a1.y);
    r.w = pack_bf16(a1.z, a1.w);
    xp[(mt * 344 + ksb) * 64 + l] = r;
}

__global__ __launch_bounds__(256) void init_out_kernel(const float* __restrict__ bias,
                                                       float* __restrict__ out) {
    int i = blockIdx.x * 256 + threadIdx.x;
    out[i] = bias[i & (OUT_F - 1)];
}

__global__ __launch_bounds__(256) void reduce_kernel(const float* __restrict__ part,
                                                     const float* __restrict__ bias,
                                                     float* __restrict__ out) {
    const int i = blockIdx.x * 256 + threadIdx.x;
    float s = bias[i & (OUT_F - 1)];
    #pragma unroll
    for (int k = 0; k < NKS; ++k) s += part[(size_t)k * (BATCH * OUT_F) + i];
    out[i] = s;
}

// block = 64 out-features x 64 batch rows, NKS=8, 2 blocks/CU (64KB LDS).
// Phase = half-super (K=128). Weights stream via global_load_lds in 1KB
// CONTIGUOUS per-wave instructions (4 rows x 256B each) -> HBM-friendly,
// with T2 XOR-swizzle applied on the GLOBAL SOURCE side (linear LDS dest,
// swizzled ds_read). Pipeline depth lives in LDS + counted vmcnt; there
// are no register-destination weight loads for the compiler to demote.
//
// Issue groups (in order):  G0 = scaleA(sup0)+stage(h0) = 12 vmem
//                           G1 = scaleB(sup0)+stage(h1) = 10 vmem
//   during even half 2s:    G  = scaleA(s+1)+stage(2s+2) = 12
//   during odd  half 2s+1:  G  = scaleB(s+1)+stage(2s+3) = 10
// wait before compute(h): in flight = G_h + G_{h+1}; retire G_h ->
//   even h: vmcnt(10), odd h: vmcnt(12), last half: vmcnt(0).
template<bool USE_PART>
__global__ __launch_bounds__(256, 2) void qlin_main(
    const intx4* __restrict__ xp,
    const int*   __restrict__ packed,
    const float* __restrict__ dd,
    const float* __restrict__ dmn_g,
    const int*   __restrict__ scales,
    const int*   __restrict__ mins,
    float*       __restrict__ part,
    float*       __restrict__ out)
{
    __shared__ intx4 xl[2][1024];   // 2 x 16KB x half-tiles   [ (wv*4+j)*64 + l ]
    __shared__ intx4 wl[2][1024];   // 2 x 16KB w half-tiles   [ wv*256 + row*16 + u' ]

    const int nb  = blockIdx.x & 63;
    const int ks  = blockIdx.x >> 6;          // 0..7
    const int tid = threadIdx.x;
    const int wv  = tid >> 6;
    const int l   = tid & 63;
    const int lo  = l & 15, hi = l >> 4;
    const int lo7 = lo & 7;

    const int o    = nb * 64 + wv * 16 + lo;  // lane's out-feature
    const int sup0 = ks < 3 ? 6 * ks : 18 + 5 * (ks - 3);
    const int nsup = ks < 3 ? 6 : 5;

    floatx4 acc[4];
    #pragma unroll
    for (int mt = 0; mt < 4; ++mt) acc[mt] = (floatx4)0.0f;

    const int*   scp = scales + o * SB_ROW + sup0 * 8;
    const int*   mnp = mins   + o * SB_ROW + sup0 * 8;
    const float* dp  = dd     + o * NSUP + sup0;
    const float* dmp = dmn_g  + o * NSUP + sup0;

    // stage one half-super into buffer b: 4 contiguous 1KB w-glds + 4 x-glds
    auto stage = [&](int sup, int par, int b) {
        #pragma unroll
        for (int j = 0; j < 4; ++j) {                 // weights: HBM, issue first
            const int row  = j * 4 + hi;              // row within wave's 16
            const int usrc = (l & 15) ^ (row & 7);    // pre-swizzled source unit
            const int* gw = packed + (size_t)(nb * 64 + wv * 16 + row) * IPR
                            + sup * 128 + par * 64 + usrc * 4;
            glds16((const void*)gw, (void*)&wl[b][wv * 256 + j * 64]);
        }
        #pragma unroll
        for (int j = 0; j < 4; ++j) {                 // x from xp: L2/L3-hot
            const intx4* gx = xp + (wv * 344 + sup * 8 + par * 4 + j) * 64 + l;
            glds16((const void*)gx, (void*)&xl[b][(wv * 4 + j) * 64]);
        }
    };

    // dequant + 16 MFMA for one half-super from buffer b (no vmem inside)
    auto compute_half = [&](int b, intx4 sv, intx4 mv, float dvv, float dmvv) {
        const float A945 = dvv * (1.0f / 945.0f);
        const float A63  = dvv * (1.0f / 63.0f);
        const int wbase  = wv * 256 + lo * 16;
        #pragma unroll
        for (int st2 = 0; st2 < 4; ++st2) {
            const float A = A945 * (float)sv[st2];
            const float B = fmaf(A63, (float)mv[st2], dmvv);
            const intx4 wr = wl[b][wbase + (((st2 * 4 + hi) ^ lo7))];
            const int v0 = wr.x, v1 = wr.y, v2 = wr.z, v3 = wr.w;
            union { intx4 i; short8 s8; } uw;
            uw.i.x = pack_bf16(fmaf((float)(v0 & 15), A, B), fmaf((float)(v0 >> 4), A, B));
            uw.i.y = pack_bf16(fmaf((float)(v1 & 15), A, B), fmaf((float)(v1 >> 4), A, B));
            uw.i.z = pack_bf16(fmaf((float)(v2 & 15), A, B), fmaf((float)(v2 >> 4), A, B));
            uw.i.w = pack_bf16(fmaf((float)(v3 & 15), A, B), fmaf((float)(v3 >> 4), A, B));

            union { intx4 i; short8 s8; } u0, u1, u2, u3;
            u0.i = xl[b][(0 * 4 + st2) * 64 + l];
            u1.i = xl[b][(1 * 4 + st2) * 64 + l];
            u2.i = xl[b][(2 * 4 + st2) * 64 + l];
            u3.i = xl[b][(3 * 4 + st2) * 64 + l];
            acc[0] = __builtin_amdgcn_mfma_f32_16x16x32_bf16(u0.s8, uw.s8, acc[0], 0, 0, 0);
            acc[1] = __builtin_amdgcn_mfma_f32_16x16x32_bf16(u1.s8, uw.s8, acc[1], 0, 0, 0);
            acc[2] = __builtin_amdgcn_mfma_f32_16x16x32_bf16(u2.s8, uw.s8, acc[2], 0, 0, 0);
            acc[3] = __builtin_amdgcn_mfma_f32_16x16x32_bf16(u3.s8, uw.s8, acc[3], 0, 0, 0);
        }
    };

    auto run = [&](auto nsc) {
        constexpr int NS = decltype(nsc)::value;
        intx4 cs0, cm0, cs1, cm1;  float cdv, cdmv;   // super s scalars
        intx4 ns0, nm0, ns1, nm1;  float ndv, ndmv;   // super s+1 (in flight)

        // ---- prologue ----
        cs0  = *(const intx4*)(scp);          // scaleA(sup0): 4 vmem
        cm0  = *(const intx4*)(mnp);
        cdv  = dp[0];
        cdmv = dmp[0];
        stage(sup0, 0, 0);                    // + 8 glds  -> G0 = 12
        group_fence();
        cs1  = *(const intx4*)(scp + 4);      // scaleB(sup0): 2 vmem
        cm1  = *(const intx4*)(mnp + 4);
        stage(sup0, 1, 1);                    // + 8 glds  -> G1 = 10
        group_fence();

        #pragma unroll
        for (int s = 0; s < NS; ++s) {
            const int sup = sup0 + s;
            // ---- first half (h = 2s, buf 0): retire G_{2s}, leave 10 ----
            asm volatile("s_waitcnt vmcnt(10)" ::: "memory");
            __builtin_amdgcn_sched_barrier(0);
            __builtin_amdgcn_s_barrier();
            compute_half(0, cs0, cm0, cdv, cdmv);
            __builtin_amdgcn_sched_barrier(0);
            __builtin_amdgcn_s_barrier();                 // all waves done with buf0
            if (s + 1 < NS) {
                ns0  = *(const intx4*)(scp + (s + 1) * 8);      // scaleA(s+1)
                nm0  = *(const intx4*)(mnp + (s + 1) * 8);
                ndv  = dp[s + 1];
                ndmv = dmp[s + 1];
                stage(sup + 1, 0, 0);                            // G = 12
            }
            group_fence();
            // ---- second half (h = 2s+1, buf 1): retire G_{2s+1} ----
            if (s + 1 < NS) { asm volatile("s_waitcnt vmcnt(12)" ::: "memory"); }
            else            { asm volatile("s_waitcnt vmcnt(0)"  ::: "memory"); }
            __builtin_amdgcn_sched_barrier(0);
            __builtin_amdgcn_s_barrier();
            compute_half(1, cs1, cm1, cdv, cdmv);
            __builtin_amdgcn_sched_barrier(0);
            __builtin_amdgcn_s_barrier();                 // all waves done with buf1
            if (s + 1 < NS) {
                ns1 = *(const intx4*)(scp + (s + 1) * 8 + 4);    // scaleB(s+1)
                nm1 = *(const intx4*)(mnp + (s + 1) * 8 + 4);
                stage(sup + 1, 1, 1);                            // G = 10
                group_fence();
                cs0 = ns0; cm0 = nm0; cdv = ndv; cdmv = ndmv;
                cs1 = ns1; cm1 = nm1;
            }
        }
    };
    if (nsup == 6) run(IC<6>{});
    else           run(IC<5>{});

    // ---- epilogue: D col = lane&15 = n (out-feature o), row = hi*4+rr = m ----
    if (USE_PART) {
        float* pbase = part + (size_t)ks * (BATCH * OUT_F) + o;
        #pragma unroll
        for (int mt = 0; mt < 4; ++mt) {
            #pragma unroll
            for (int rr = 0; rr < 4; ++rr)
                pbase[(mt * 16 + hi * 4 + rr) * OUT_F] = acc[mt][rr];
        }
    } else {
        #pragma unroll
        for (int mt = 0; mt < 4; ++mt) {
            #pragma unroll
            for (int rr = 0; rr < 4; ++rr)
                atomicAdd(out + (mt * 16 + hi * 4 + rr) * OUT_F + o, acc[mt][rr]);
        }
    }
}

extern "C" void kernel_launch(void* const* d_in, const int* in_sizes, int n_in,
                              void* d_out, int out_size, void* d_ws, size_t ws_size,
                              hipStream_t stream) {
    (void)in_sizes; (void)n_in; (void)out_size;
    const float* x      = (const float*)d_in[0];
    const int*   packed = (const int*)d_in[1];
    const float* d      = (const float*)d_in[2];
    const float* dmin   = (const float*)d_in[3];
    const int*   scales = (const int*)d_in[4];
    const int*   mins   = (const int*)d_in[5];
    const float* bias   = (const float*)d_in[6];
    float* out = (float*)d_out;

    const bool has_part = ws_size >= (size_t)WS_FULL;
    intx4* xp   = (intx4*)d_ws;
    float* part = (float*)((char*)d_ws + XP_BYTES);

    xprep_kernel<<<344, 256, 0, stream>>>(x, xp);

    if (has_part) {
        qlin_main<true><<<64 * NKS, 256, 0, stream>>>(
            xp, packed, d, dmin, scales, mins, part, out);
        reduce_kernel<<<(BATCH * OUT_F) / 256, 256, 0, stream>>>(part, bias, out);
    } else {
        init_out_kernel<<<(BATCH * OUT_F) / 256, 256, 0, stream>>>(bias, out);
        qlin_main<false><<<64 * NKS, 256, 0, stream>>>(
            xp, packed, d, dmin, scales, mins, part, out);
    }
}

// Round 7
// 165.820 us; speedup vs baseline: 1.0312x; 1.0312x over previous
//
#include <hip/hip_runtime.h>
#include <stdint.h>

#define OUT_F   4096
#define IN_F    11008
#define BATCH   64
#define NSUP    43                  // super-blocks per row
#define SB_ROW  344                 // sub-blocks per row
#define IPR     5504                // int32 elements per weight row
#define NKS     12                  // K-splits -> 64 x 12 = 768 blocks = 3/CU exactly
#define XP_BYTES   (4 * 344 * 64 * 16)              // 1,409,024 B
#define PART_ELEMS ((size_t)NKS * BATCH * OUT_F)
#define WS_FULL    (XP_BYTES + PART_ELEMS * 4)

typedef __attribute__((ext_vector_type(8))) short  short8;
typedef __attribute__((ext_vector_type(4))) float  floatx4;
typedef __attribute__((ext_vector_type(4))) int    intx4;

__device__ __forceinline__ unsigned pack_bf16(float f0, float f1) {
    return __builtin_amdgcn_perm(__float_as_uint(f1), __float_as_uint(f0), 0x07060302u);
}

// ---- pre-pack x into MFMA A-fragment order: xp[(mt*344 + ksb)*64 + l] ----
__global__ __launch_bounds__(256) void xprep_kernel(const float* __restrict__ x,
                                                    intx4* __restrict__ xp) {
    const int ksb = blockIdx.x;            // 0..343
    const int mt  = threadIdx.x >> 6;
    const int l   = threadIdx.x & 63;
    const int lo  = l & 15, hi = l >> 4;
    const float* src = x + (mt * 16 + lo) * IN_F + ksb * 32 + hi * 8;
    floatx4 a0 = *(const floatx4*)src;
    floatx4 a1 = *(const floatx4*)(src + 4);
    intx4 r;
    r.x = pack_bf16(a0.x, a0.y);
    r.y = pack_bf16(a0.z, a0.w);
    r.z = pack_bf16(a1.x, a1.y);
    r.w = pack_bf16(a1.z, a1.w);
    xp[(mt * 344 + ksb) * 64 + l] = r;
}

__global__ __launch_bounds__(256) void init_out_kernel(const float* __restrict__ bias,
                                                       float* __restrict__ out) {
    int i = blockIdx.x * 256 + threadIdx.x;
    out[i] = bias[i & (OUT_F - 1)];
}

__global__ __launch_bounds__(256) void reduce_kernel(const float* __restrict__ part,
                                                     const float* __restrict__ bias,
                                                     float* __restrict__ out) {
    const int i = blockIdx.x * 256 + threadIdx.x;
    float s = bias[i & (OUT_F - 1)];
    #pragma unroll
    for (int k = 0; k < NKS; ++k) s += part[(size_t)k * (BATCH * OUT_F) + i];
    out[i] = s;
}

// block = 64 out-features x 64 batch rows. Per super-block: stage xf/scales/d in
// LDS ONCE (kills the 4x intra-block L1 redundancy), braw stays per-wave regs.
template<bool USE_PART>
__global__ __launch_bounds__(256, 3) void qlin_main(
    const intx4* __restrict__ xp,
    const int*   __restrict__ packed,
    const float* __restrict__ dd,
    const float* __restrict__ dmn_g,
    const int*   __restrict__ scales,
    const int*   __restrict__ mins,
    float*       __restrict__ part,
    float*       __restrict__ out)
{
    __shared__ intx4 xfs[2048];     // 32KB  [mt*512 + st*64 + l]
    __shared__ int   scs[512];      // 2KB   [r*8 + j]
    __shared__ int   mns[512];      // 2KB
    __shared__ float dsx[64];       // per-row d
    __shared__ float dmx[64];       // per-row dmin

    const int nb  = blockIdx.x & 63;
    const int ks  = blockIdx.x >> 6;          // 0..11
    const int tid = threadIdx.x;
    const int w   = tid >> 6;
    const int l   = tid & 63;
    const int lo  = l & 15, hi = l >> 4;

    const int o    = nb * 64 + w * 16 + lo;   // lane's out-feature
    const int r    = w * 16 + lo;             // row within block
    const int sup0 = ks < 7 ? 4 * ks : 28 + 3 * (ks - 7);
    const int nsup = ks < 7 ? 4 : 3;

    floatx4 acc[4];
    #pragma unroll
    for (int mt = 0; mt < 4; ++mt) acc[mt] = (floatx4)0.0f;

    const int* bp0 = packed + o * IPR + sup0 * 128 + hi * 4;
    const int tr = tid & 63;                  // staging row for this thread
    const int og = nb * 64 + tr;

    #pragma unroll 1
    for (int s = 0; s < nsup; ++s) {
        const int sup = sup0 + s;

        // ---- per-wave unique weights: issue first (HBM, overlaps staging) ----
        intx4 br[8];
        #pragma unroll
        for (int st = 0; st < 8; ++st)
            br[st] = __builtin_nontemporal_load((const intx4*)(bp0 + s * 128 + st * 16));

        // ---- staging loads into VGPRs (coalesced, L2-hot) ----
        intx4 xtmp[8];
        const intx4* xsrc = xp + sup * 512;
        #pragma unroll
        for (int i = 0; i < 8; ++i) {
            const int idx = i * 256 + tid;
            xtmp[i] = xsrc[(idx >> 9) * 22016 + (idx & 511)];
        }
        intx4 sct0, sct1;
        float dtmp = 0.0f;
        if (w == 0) {
            sct0 = *(const intx4*)(scales + og * SB_ROW + sup * 8);
            sct1 = *(const intx4*)(scales + og * SB_ROW + sup * 8 + 4);
        } else if (w == 1) {
            sct0 = *(const intx4*)(mins + og * SB_ROW + sup * 8);
            sct1 = *(const intx4*)(mins + og * SB_ROW + sup * 8 + 4);
        } else if (w == 2) {
            dtmp = dd[og * NSUP + sup];
        } else {
            dtmp = dmn_g[og * NSUP + sup];
        }

        // ---- commit to LDS ----
        if (s > 0) __syncthreads();           // previous sup's readers done
        #pragma unroll
        for (int i = 0; i < 8; ++i)
            xfs[i * 256 + tid] = xtmp[i];
        if (w == 0) {
            *(intx4*)&scs[tr * 8]     = sct0;
            *(intx4*)&scs[tr * 8 + 4] = sct1;
        } else if (w == 1) {
            *(intx4*)&mns[tr * 8]     = sct0;
            *(intx4*)&mns[tr * 8 + 4] = sct1;
        } else if (w == 2) {
            dsx[tr] = dtmp;
        } else {
            dmx[tr] = dtmp;
        }
        __syncthreads();

        // ---- per-lane dequant constants from LDS ----
        const float dv   = dsx[r];
        const float dmv  = dmx[r];
        const float A945 = dv * (1.0f / 945.0f);
        const float A63  = dv * (1.0f / 63.0f);
        const intx4 s0 = *(const intx4*)&scs[r * 8];
        const intx4 s1 = *(const intx4*)&scs[r * 8 + 4];
        const intx4 m0 = *(const intx4*)&mns[r * 8];
        const intx4 m1 = *(const intx4*)&mns[r * 8 + 4];

        // ---- 8 K-steps: ds_read fragments + dequant + MFMA ----
        #pragma unroll
        for (int st = 0; st < 8; ++st) {
            const int scv = (st < 4) ? s0[st & 3] : s1[st & 3];
            const int mnv = (st < 4) ? m0[st & 3] : m1[st & 3];
            const float A = A945 * (float)scv;
            const float B = fmaf(A63, (float)mnv, dmv);
            const int v0 = br[st].x, v1 = br[st].y, v2 = br[st].z, v3 = br[st].w;
            union { intx4 i; short8 s8; } uw;
            uw.i.x = pack_bf16(fmaf((float)(v0 & 15), A, B), fmaf((float)(v0 >> 4), A, B));
            uw.i.y = pack_bf16(fmaf((float)(v1 & 15), A, B), fmaf((float)(v1 >> 4), A, B));
            uw.i.z = pack_bf16(fmaf((float)(v2 & 15), A, B), fmaf((float)(v2 >> 4), A, B));
            uw.i.w = pack_bf16(fmaf((float)(v3 & 15), A, B), fmaf((float)(v3 >> 4), A, B));

            union { intx4 i; short8 s8; } u0, u1, u2, u3;
            u0.i = xfs[0 * 512 + st * 64 + l];
            u1.i = xfs[1 * 512 + st * 64 + l];
            u2.i = xfs[2 * 512 + st * 64 + l];
            u3.i = xfs[3 * 512 + st * 64 + l];
            acc[0] = __builtin_amdgcn_mfma_f32_16x16x32_bf16(u0.s8, uw.s8, acc[0], 0, 0, 0);
            acc[1] = __builtin_amdgcn_mfma_f32_16x16x32_bf16(u1.s8, uw.s8, acc[1], 0, 0, 0);
            acc[2] = __builtin_amdgcn_mfma_f32_16x16x32_bf16(u2.s8, uw.s8, acc[2], 0, 0, 0);
            acc[3] = __builtin_amdgcn_mfma_f32_16x16x32_bf16(u3.s8, uw.s8, acc[3], 0, 0, 0);
        }
    }

    // ---- epilogue: D col = lane&15 = n (out-feature o), row = hi*4+rr = m ----
    if (USE_PART) {
        float* pbase = part + (size_t)ks * (BATCH * OUT_F) + o;
        #pragma unroll
        for (int mt = 0; mt < 4; ++mt) {
            #pragma unroll
            for (int rr = 0; rr < 4; ++rr)
                pbase[(mt * 16 + hi * 4 + rr) * OUT_F] = acc[mt][rr];
        }
    } else {
        #pragma unroll
        for (int mt = 0; mt < 4; ++mt) {
            #pragma unroll
            for (int rr = 0; rr < 4; ++rr)
                atomicAdd(out + (mt * 16 + hi * 4 + rr) * OUT_F + o, acc[mt][rr]);
        }
    }
}

extern "C" void kernel_launch(void* const* d_in, const int* in_sizes, int n_in,
                              void* d_out, int out_size, void* d_ws, size_t ws_size,
                              hipStream_t stream) {
    (void)in_sizes; (void)n_in; (void)out_size;
    const float* x      = (const float*)d_in[0];
    const int*   packed = (const int*)d_in[1];
    const float* d      = (const float*)d_in[2];
    const float* dmin   = (const float*)d_in[3];
    const int*   scales = (const int*)d_in[4];
    const int*   mins   = (const int*)d_in[5];
    const float* bias   = (const float*)d_in[6];
    float* out = (float*)d_out;

    const bool has_part = ws_size >= (size_t)WS_FULL;
    intx4* xp   = (intx4*)d_ws;
    float* part = (float*)((char*)d_ws + XP_BYTES);

    xprep_kernel<<<344, 256, 0, stream>>>(x, xp);

    if (has_part) {
        qlin_main<true><<<64 * NKS, 256, 0, stream>>>(
            xp, packed, d, dmin, scales, mins, part, out);
        reduce_kernel<<<(BATCH * OUT_F) / 256, 256, 0, stream>>>(part, bias, out);
    } else {
        init_out_kernel<<<(BATCH * OUT_F) / 256, 256, 0, stream>>>(bias, out);
        qlin_main<false><<<64 * NKS, 256, 0, stream>>>(
            xp, packed, d, dmin, scales, mins, part, out);
    }
}